// Round 1
// baseline (802.912 us; speedup 1.0000x reference)
//
// SGBlock fused forward, MI355X (gfx950).
// R0: correctness-first full implementation; MLP GEMMs in bf16 MFMA (m97 structure).
#include <hip/hip_runtime.h>
#include <hip/hip_bf16.h>

typedef unsigned short u16;
typedef __bf16 bf16x8 __attribute__((ext_vector_type(8)));
typedef float f32x4 __attribute__((ext_vector_type(4)));

#define B_    128
#define N_TOK 320
#define D_    768
#define M_TOT (B_ * N_TOK)   // 40960

// ---------------- helpers ----------------
__device__ __forceinline__ u16 f2b(float x) {
  __hip_bfloat16 t = __float2bfloat16(x);
  return *reinterpret_cast<u16*>(&t);
}

typedef const __attribute__((address_space(1))) void* gas1_t;
typedef __attribute__((address_space(3))) void* las3_t;
__device__ __forceinline__ void gll16(const void* g, void* l) {
  __builtin_amdgcn_global_load_lds((gas1_t)g, (las3_t)l, 16, 0, 0);
}

// two-value block reduction over 256 threads (4 waves)
__device__ __forceinline__ void block_reduce2(float& a, float& b, float* red, int t) {
  #pragma unroll
  for (int off = 32; off >= 1; off >>= 1) {
    a += __shfl_xor(a, off);
    b += __shfl_xor(b, off);
  }
  int wv = t >> 6;
  __syncthreads();              // protect red from previous use
  if ((t & 63) == 0) { red[wv] = a; red[4 + wv] = b; }
  __syncthreads();
  a = red[0] + red[1] + red[2] + red[3];
  b = red[4] + red[5] + red[6] + red[7];
}

// ---------------- 1: weight transpose fp32[K][N] -> bf16[N][K] ----------------
__global__ __launch_bounds__(256) void k_transpose_bf16(const float* __restrict__ in,
                                                        u16* __restrict__ out) {
  __shared__ float tile[32][33];
  int c0 = blockIdx.x * 32, r0 = blockIdx.y * 32;
  int tx = threadIdx.x, ty = threadIdx.y;
  #pragma unroll
  for (int k = 0; k < 4; k++)
    tile[ty + k * 8][tx] = in[(size_t)(r0 + ty + k * 8) * 768 + c0 + tx];
  __syncthreads();
  #pragma unroll
  for (int k = 0; k < 4; k++)
    out[(size_t)(c0 + ty + k * 8) * 768 + r0 + tx] = f2b(tile[tx][ty + k * 8]);
}

// ---------------- 2: per-token y = relu(x@lin_w+b), xa = x@ad_w+b, qkv ----------------
__global__ __launch_bounds__(256) void k_token_a(
    const float* __restrict__ x,
    const float* __restrict__ lin_w, const float* __restrict__ lin_b,
    const float* __restrict__ qkv_w, const float* __restrict__ qkv_b,
    const float* __restrict__ ad_w, const float* __restrict__ ad_b,
    float* __restrict__ y_out, float* __restrict__ xa_out,
    float* __restrict__ q_out, float* __restrict__ k_out, float* __restrict__ v_out) {
  __shared__ __align__(16) float w_lds[16 * 768];   // [j][e], j<8: lin_w col, j>=8: ad_w col
  int t = threadIdx.x;
  for (int i = t; i < 6144; i += 256) {
    w_lds[(i & 7) * 768 + (i >> 3)] = lin_w[i];
    w_lds[((i & 7) + 8) * 768 + (i >> 3)] = ad_w[i];
  }
  __syncthreads();
  int wave = t >> 6, lane = t & 63;
  for (int it = 0; it < 10; ++it) {
    int tok = blockIdx.x * 4 + wave + it * 4096;
    const float* xr = x + (size_t)tok * 768;
    float p[16];
    #pragma unroll
    for (int j = 0; j < 16; j++) p[j] = 0.f;
    #pragma unroll
    for (int u = 0; u < 3; u++) {
      float4 xv = *reinterpret_cast<const float4*>(xr + u * 256 + lane * 4);
      #pragma unroll
      for (int j = 0; j < 16; j++) {
        float4 wv = *reinterpret_cast<const float4*>(&w_lds[j * 768 + u * 256 + lane * 4]);
        p[j] += xv.x * wv.x + xv.y * wv.y + xv.z * wv.z + xv.w * wv.w;
      }
    }
    #pragma unroll
    for (int j = 0; j < 16; j++) {
      #pragma unroll
      for (int off = 32; off >= 1; off >>= 1) p[j] += __shfl_xor(p[j], off);
    }
    float yv[8];
    #pragma unroll
    for (int j = 0; j < 8; j++) yv[j] = fmaxf(p[j] + lin_b[j], 0.f);
    if (lane == 0) {
      #pragma unroll
      for (int j = 0; j < 8; j++) {
        y_out[(size_t)tok * 8 + j] = yv[j];
        xa_out[(size_t)tok * 8 + j] = p[8 + j] + ad_b[j];
      }
    }
    if (lane < 24) {
      float o = qkv_b[lane];
      #pragma unroll
      for (int j = 0; j < 8; j++) o += yv[j] * qkv_w[j * 24 + lane];
      int b = tok / 320, n = tok % 320;
      int hh = lane & 7;
      size_t idx = ((size_t)b * 8 + hh) * 320 + n;
      if (lane < 8) q_out[idx] = o;
      else if (lane < 16) k_out[idx] = o;
      else v_out[idx] = o;
    }
  }
}

// ---------------- 3: attention (dh=1): av[b,n,h] = softmax_m(q_n k_m) . v ----------------
__global__ __launch_bounds__(320) void k_attn(
    const float* __restrict__ q, const float* __restrict__ k,
    const float* __restrict__ v, float* __restrict__ av) {
  __shared__ float ks[320], vs[320];
  __shared__ float red[12];
  int bh = blockIdx.x;          // b*8+h
  int n = threadIdx.x;          // 0..319
  float kk = k[(size_t)bh * 320 + n];
  ks[n] = kk;
  vs[n] = v[(size_t)bh * 320 + n];
  float qn = q[(size_t)bh * 320 + n];
  float mx = kk, mn = kk;
  #pragma unroll
  for (int off = 32; off >= 1; off >>= 1) {
    mx = fmaxf(mx, __shfl_xor(mx, off));
    mn = fminf(mn, __shfl_xor(mn, off));
  }
  int wave = n >> 6;
  if ((n & 63) == 0) { red[wave] = mx; red[5 + wave] = mn; }
  __syncthreads();
  if (n == 0) {
    float a = red[0], b = red[5];
    #pragma unroll
    for (int w = 1; w < 5; w++) { a = fmaxf(a, red[w]); b = fminf(b, red[5 + w]); }
    red[10] = a; red[11] = b;
  }
  __syncthreads();
  float kmax = red[10], kmin = red[11];
  float m1 = fmaxf(qn * kmax, qn * kmin);
  float se = 0.f, sv = 0.f;
  for (int m = 0; m < 320; m++) {
    float e = __expf(qn * ks[m] - m1);
    se += e;
    sv += e * vs[m];
  }
  int b_ = bh >> 3, h_ = bh & 7;
  av[(((size_t)b_ * 320) + n) * 8 + h_] = sv / se;
}

// ---------------- 4: residual + LN + LN2 -> h (bf16) ----------------
__global__ __launch_bounds__(256) void k_token_c(
    const float* __restrict__ x, const float* __restrict__ y_ws, const float* __restrict__ av_ws,
    const float* __restrict__ proj_w, const float* __restrict__ proj_b,
    const float* __restrict__ end_w, const float* __restrict__ end_b,
    const float* __restrict__ g1ln, const float* __restrict__ b1ln,
    const float* __restrict__ g2ln, const float* __restrict__ b2ln,
    u16* __restrict__ hout) {
  __shared__ float red[8];
  size_t tok = blockIdx.x;
  int t = threadIdx.x;
  float u[8];
  #pragma unroll
  for (int o = 0; o < 8; o++) {
    float a = proj_b[o];
    #pragma unroll
    for (int j = 0; j < 8; j++) a += av_ws[tok * 8 + j] * proj_w[j * 8 + o];
    u[o] = a + y_ws[tok * 8 + o];
  }
  float tv[3];
  #pragma unroll
  for (int c = 0; c < 3; c++) {
    int d = t + c * 256;
    float a = x[tok * 768 + d] + end_b[d];
    #pragma unroll
    for (int j = 0; j < 8; j++) a += u[j] * end_w[j * 768 + d];
    tv[c] = a;
  }
  float s = tv[0] + tv[1] + tv[2];
  float s2 = tv[0] * tv[0] + tv[1] * tv[1] + tv[2] * tv[2];
  block_reduce2(s, s2, red, t);
  float m1 = s * (1.f / 768.f);
  float inv1 = rsqrtf(fmaxf(s2 * (1.f / 768.f) - m1 * m1, 0.f) + 1e-5f);
  float x0[3];
  #pragma unroll
  for (int c = 0; c < 3; c++) {
    int d = t + c * 256;
    x0[c] = (tv[c] - m1) * inv1 * g1ln[d] + b1ln[d];
  }
  s = x0[0] + x0[1] + x0[2];
  s2 = x0[0] * x0[0] + x0[1] * x0[1] + x0[2] * x0[2];
  block_reduce2(s, s2, red, t);
  float m2 = s * (1.f / 768.f);
  float inv2 = rsqrtf(fmaxf(s2 * (1.f / 768.f) - m2 * m2, 0.f) + 1e-5f);
  #pragma unroll
  for (int c = 0; c < 3; c++) {
    int d = t + c * 256;
    float hv = (x0[c] - m2) * inv2 * g2ln[d] + b2ln[d];
    hout[tok * 768 + d] = f2b(hv);
  }
}

// ---------------- 5/6: adapter branch (conv1x1+bn+relu, SGN via direct DFT, convs, bns) ----------------
template <int S>
__global__ __launch_bounds__(256) void k_adapter(
    const float* __restrict__ xa,
    const float* __restrict__ bw, const float* __restrict__ bb,
    const float* __restrict__ bng0, const float* __restrict__ bnb0,
    const float* __restrict__ cw,
    const float* __restrict__ crw, const float* __restrict__ crb,
    const float* __restrict__ ciw, const float* __restrict__ cib,
    const float* __restrict__ bn1g, const float* __restrict__ bn1b,
    const float* __restrict__ bn2g, const float* __restrict__ bn2b,
    const float* __restrict__ cvw, const float* __restrict__ cvb,
    const float* __restrict__ c3w, const float* __restrict__ c3b,
    const float* __restrict__ bng, const float* __restrict__ bnb,
    float* __restrict__ crout, int tok_off) {
  constexpr int NF = S / 2 + 1;
  constexpr int P = S * S;
  constexpr int NFREQ = S * NF * 8;
  __shared__ float xr[8 * P];
  __shared__ float x1[8 * P];
  __shared__ float xo[8 * P];
  __shared__ float bufA[NFREQ * 2];
  __shared__ float bufB[NFREQ * 2];
  __shared__ float cosT[S], sinT[S];
  const int b = blockIdx.x, t = threadIdx.x;
  const float binv = rsqrtf(1.f + 1e-5f);
  if (t < S) {
    float ang = 6.28318530717958647692f * (float)t / (float)S;
    cosT[t] = cosf(ang);
    sinT[t] = sinf(ang);
  }
  for (int i = t; i < 8 * P; i += 256) {
    int c = i / P, p = i % P;
    xr[i] = xa[((size_t)b * N_TOK + tok_off + p) * 8 + c];
  }
  __syncthreads();
  // b-conv 1x1 + bn + relu -> x1
  for (int i = t; i < 8 * P; i += 256) {
    int c = i / P, p = i % P;
    float a = bb[c];
    #pragma unroll
    for (int j = 0; j < 8; j++) a += xr[j * P + p] * bw[c * 8 + j];
    a = a * (bng0[c] * binv) + bnb0[c];
    x1[i] = fmaxf(a, 0.f);
  }
  __syncthreads();
  // forward rfft over h (axis2): Ra[w][v][c]
  for (int i = t; i < NFREQ; i += 256) {
    int c = i & 7, v = (i >> 3) % NF, w = i / (8 * NF);
    float re = 0.f, im = 0.f;
    #pragma unroll
    for (int h = 0; h < S; h++) {
      float xv = x1[c * P + h * S + w];
      int idx = (v * h) % S;
      re += xv * cosT[idx];
      im -= xv * sinT[idx];
    }
    bufA[i * 2] = re;
    bufA[i * 2 + 1] = im;
  }
  __syncthreads();
  // forward fft over w (axis1) -> F[u][v][c], ortho scale 1/S
  for (int i = t; i < NFREQ; i += 256) {
    int c = i & 7, v = (i >> 3) % NF, u = i / (8 * NF);
    float re = 0.f, im = 0.f;
    #pragma unroll
    for (int w = 0; w < S; w++) {
      float ar = bufA[((w * NF + v) * 8 + c) * 2];
      float ai = bufA[((w * NF + v) * 8 + c) * 2 + 1];
      int idx = (u * w) % S;
      float cs = cosT[idx], sn = sinT[idx];
      re += ar * cs + ai * sn;
      im += ai * cs - ar * sn;
    }
    bufB[i * 2] = re * (1.f / S);
    bufB[i * 2 + 1] = im * (1.f / S);
  }
  __syncthreads();
  // channel mix (conv1x1 + bn + relu on re/im), then complex weight cw
  for (int i = t; i < NFREQ; i += 256) {
    int c = i & 7;
    int uv = i >> 3;
    float fr = crb[c], fi = cib[c];
    #pragma unroll
    for (int j = 0; j < 8; j++) {
      fr += bufB[(uv * 8 + j) * 2] * crw[c * 8 + j];
      fi += bufB[(uv * 8 + j) * 2 + 1] * ciw[c * 8 + j];
    }
    fr = fmaxf(fr * (bn1g[c] * binv) + bn1b[c], 0.f);
    fi = fmaxf(fi * (bn2g[c] * binv) + bn2b[c], 0.f);
    float cwr = cw[i * 2], cwi = cw[i * 2 + 1];
    bufA[i * 2] = fr * cwr - fi * cwi;
    bufA[i * 2 + 1] = fr * cwi + fi * cwr;
  }
  __syncthreads();
  // inverse fft over u -> T[w][v][c]
  for (int i = t; i < NFREQ; i += 256) {
    int c = i & 7, v = (i >> 3) % NF, w = i / (8 * NF);
    float re = 0.f, im = 0.f;
    #pragma unroll
    for (int u = 0; u < S; u++) {
      float gr = bufA[((u * NF + v) * 8 + c) * 2];
      float gi = bufA[((u * NF + v) * 8 + c) * 2 + 1];
      int idx = (u * w) % S;
      float cs = cosT[idx], sn = sinT[idx];
      re += gr * cs - gi * sn;
      im += gi * cs + gr * sn;
    }
    bufB[((w * NF + v) * 8 + c) * 2] = re;
    bufB[((w * NF + v) * 8 + c) * 2 + 1] = im;
  }
  __syncthreads();
  // inverse real transform over v (c2r: DC/Nyquist imag discarded), scale 1/S, + x1
  for (int i = t; i < 8 * P; i += 256) {
    int c = i / P, p = i % P, h = p / S, w = p % S;
    float acc = bufB[((w * NF + 0) * 8 + c) * 2];
    float ny = bufB[((w * NF + (NF - 1)) * 8 + c) * 2];
    acc += (h & 1) ? -ny : ny;
    #pragma unroll
    for (int v = 1; v < NF - 1; v++) {
      int idx = (v * h) % S;
      acc += 2.f * (bufB[((w * NF + v) * 8 + c) * 2] * cosT[idx] -
                    bufB[((w * NF + v) * 8 + c) * 2 + 1] * sinT[idx]);
    }
    xo[i] = acc * (1.f / S) + x1[i];
  }
  __syncthreads();
  // conv1x1+bn+relu, + conv3x3(xr), bn+relu, store tokens
  for (int i = t; i < 8 * P; i += 256) {
    int c = i / P, p = i % P, h = p / S, w = p % S;
    float a = cvb[c];
    #pragma unroll
    for (int j = 0; j < 8; j++) a += xo[j * P + p] * cvw[c * 8 + j];
    a = fmaxf(a * (bng[c] * binv) + bnb[c], 0.f);
    float x2 = c3b[c];
    #pragma unroll
    for (int j = 0; j < 8; j++) {
      #pragma unroll
      for (int dy = 0; dy < 3; dy++) {
        int hh = h + dy - 1;
        if (hh < 0 || hh >= S) continue;
        #pragma unroll
        for (int dx = 0; dx < 3; dx++) {
          int ww = w + dx - 1;
          if (ww < 0 || ww >= S) continue;
          x2 += xr[j * P + hh * S + ww] * c3w[((c * 8 + j) * 3 + dy) * 3 + dx];
        }
      }
    }
    float fin = (a + x2) * (bng[c] * binv) + bnb[c];
    crout[((size_t)b * N_TOK + tok_off + p) * 8 + c] = fmaxf(fin, 0.f);
  }
}

// ---------------- 7/8: bf16 MFMA GEMM, 128x128 tile, BK=32 (m97 structure) ----------------
// MODE 1: out_bf = bf16(gelu_exact(acc + bias))       (GEMM1)
// MODE 2: out_f  = acc + bias + au_b + cr@au_w        (GEMM2 + adapter epilogue)
template <int MODE>
__global__ __launch_bounds__(256) void k_gemm(
    const u16* __restrict__ A, const u16* __restrict__ Bt,
    const float* __restrict__ bias,
    u16* __restrict__ obf, float* __restrict__ ofp,
    const float* __restrict__ au_w, const float* __restrict__ au_b,
    const float* __restrict__ cr) {
  __shared__ __align__(16) u16 As[128 * 32];
  __shared__ __align__(16) u16 Bs[128 * 32];
  int bid = blockIdx.x;
  int bm = bid / 6, bn = bid % 6;
  int m0 = bm * 128, n0 = bn * 128;
  int t = threadIdx.x, wave = t >> 6, lane = t & 63;
  int wr = wave >> 1, wc = wave & 1;
  const int l15 = lane & 15, l4 = lane >> 4;
  f32x4 acc[4][4];
  #pragma unroll
  for (int mi = 0; mi < 4; mi++)
    #pragma unroll
    for (int ni = 0; ni < 4; ni++) {
      f32x4 z = {0.f, 0.f, 0.f, 0.f};
      acc[mi][ni] = z;
    }
  for (int k0 = 0; k0 < 768; k0 += 32) {
    #pragma unroll
    for (int i = 0; i < 2; i++) {
      int chunk = i * 256 + t;
      int r = chunk >> 2, kp = (chunk & 3) * 8;
      gll16(A + (size_t)(m0 + r) * 768 + k0 + kp, (void*)&As[(i * 256 + wave * 64) * 8]);
      gll16(Bt + (size_t)(n0 + r) * 768 + k0 + kp, (void*)&Bs[(i * 256 + wave * 64) * 8]);
    }
    __syncthreads();
    bf16x8 af[4], bfr[4];
    #pragma unroll
    for (int mi = 0; mi < 4; mi++)
      af[mi] = *reinterpret_cast<const bf16x8*>(&As[(wr * 64 + mi * 16 + l15) * 32 + l4 * 8]);
    #pragma unroll
    for (int ni = 0; ni < 4; ni++)
      bfr[ni] = *reinterpret_cast<const bf16x8*>(&Bs[(wc * 64 + ni * 16 + l15) * 32 + l4 * 8]);
    #pragma unroll
    for (int mi = 0; mi < 4; mi++)
      #pragma unroll
      for (int ni = 0; ni < 4; ni++)
        acc[mi][ni] = __builtin_amdgcn_mfma_f32_16x16x32_bf16(af[mi], bfr[ni], acc[mi][ni], 0, 0, 0);
    __syncthreads();
  }
  // epilogue: C/D layout col = lane&15, row = 4*(lane>>4)+reg
  #pragma unroll
  for (int mi = 0; mi < 4; mi++) {
    #pragma unroll
    for (int ni = 0; ni < 4; ni++) {
      int colg = n0 + wc * 64 + ni * 16 + l15;
      #pragma unroll
      for (int rg = 0; rg < 4; rg++) {
        int rowg = m0 + wr * 64 + mi * 16 + l4 * 4 + rg;
        float vv = acc[mi][ni][rg] + bias[colg];
        if constexpr (MODE == 1) {
          vv = 0.5f * vv * (1.f + erff(vv * 0.70710678118654752f));
          obf[(size_t)rowg * 768 + colg] = f2b(vv);
        } else {
          vv += au_b[colg];
          const float* crr = cr + (size_t)rowg * 8;
          #pragma unroll
          for (int j = 0; j < 8; j++) vv += crr[j] * au_w[j * 768 + colg];
          ofp[(size_t)rowg * 768 + colg] = vv;
        }
      }
    }
  }
}

// ---------------- launch ----------------
extern "C" void kernel_launch(void* const* d_in, const int* in_sizes, int n_in,
                              void* d_out, int out_size, void* d_ws, size_t ws_size,
                              hipStream_t stream) {
  const float* x        = (const float*)d_in[0];
  const float* am_lin_w = (const float*)d_in[1];
  const float* am_lin_b = (const float*)d_in[2];
  const float* am_qkv_w = (const float*)d_in[3];
  const float* am_qkv_b = (const float*)d_in[4];
  const float* am_proj_w= (const float*)d_in[5];
  const float* am_proj_b= (const float*)d_in[6];
  const float* am_end_w = (const float*)d_in[7];
  const float* am_end_b = (const float*)d_in[8];
  const float* am_ln_g  = (const float*)d_in[9];
  const float* am_ln_b  = (const float*)d_in[10];
  const float* ln2_g    = (const float*)d_in[11];
  const float* ln2_b    = (const float*)d_in[12];
  const float* fc1_w    = (const float*)d_in[13];
  const float* fc1_b    = (const float*)d_in[14];
  const float* fc2_w    = (const float*)d_in[15];
  const float* fc2_b    = (const float*)d_in[16];
  const float* ad_w     = (const float*)d_in[17];
  const float* ad_b     = (const float*)d_in[18];
  const float* au_w     = (const float*)d_in[19];
  const float* au_b     = (const float*)d_in[20];
  const float* b1_w     = (const float*)d_in[21];
  const float* b1_b     = (const float*)d_in[22];
  const float* b1_bn_g  = (const float*)d_in[23];
  const float* b1_bn_b  = (const float*)d_in[24];
  const float* b2_w     = (const float*)d_in[25];
  const float* b2_b     = (const float*)d_in[26];
  const float* b2_bn_g  = (const float*)d_in[27];
  const float* b2_bn_b  = (const float*)d_in[28];
  const float* sx_cw    = (const float*)d_in[29];
  const float* sx_cr_w  = (const float*)d_in[30];
  const float* sx_cr_b  = (const float*)d_in[31];
  const float* sx_ci_w  = (const float*)d_in[32];
  const float* sx_ci_b  = (const float*)d_in[33];
  const float* sx_bn1_g = (const float*)d_in[34];
  const float* sx_bn1_b = (const float*)d_in[35];
  const float* sx_bn2_g = (const float*)d_in[36];
  const float* sx_bn2_b = (const float*)d_in[37];
  const float* sz_cw    = (const float*)d_in[38];
  const float* sz_cr_w  = (const float*)d_in[39];
  const float* sz_cr_b  = (const float*)d_in[40];
  const float* sz_ci_w  = (const float*)d_in[41];
  const float* sz_ci_b  = (const float*)d_in[42];
  const float* sz_bn1_g = (const float*)d_in[43];
  const float* sz_bn1_b = (const float*)d_in[44];
  const float* sz_bn2_g = (const float*)d_in[45];
  const float* sz_bn2_b = (const float*)d_in[46];
  const float* c1_w     = (const float*)d_in[47];
  const float* c1_b     = (const float*)d_in[48];
  const float* c2_w     = (const float*)d_in[49];
  const float* c2_b     = (const float*)d_in[50];
  const float* c3_w     = (const float*)d_in[51];
  const float* c3_b     = (const float*)d_in[52];
  const float* c4_w     = (const float*)d_in[53];
  const float* c4_b     = (const float*)d_in[54];
  const float* bn_g     = (const float*)d_in[55];
  const float* bn_b     = (const float*)d_in[56];

  char* ws = (char*)d_ws;
  constexpr size_t H_OFF   = 0;                         // h bf16 [40960][768]
  constexpr size_t G1_OFF  = 62914560;                  // g1 bf16 [40960][768]
  constexpr size_t W1T_OFF = 125829120;                 // fc1_w^T bf16 [768][768]
  constexpr size_t W2T_OFF = W1T_OFF + 1179648;
  constexpr size_t Y_OFF   = W2T_OFF + 1179648;         // y [40960][8] f32
  constexpr size_t XA_OFF  = Y_OFF + 1310720;
  constexpr size_t AV_OFF  = XA_OFF + 1310720;
  constexpr size_t Q_OFF   = AV_OFF + 1310720;
  constexpr size_t K_OFF   = Q_OFF + 1310720;
  constexpr size_t V_OFF   = K_OFF + 1310720;
  constexpr size_t CR_OFF  = V_OFF + 1310720;

  u16* h_ws   = (u16*)(ws + H_OFF);
  u16* g1_ws  = (u16*)(ws + G1_OFF);
  u16* w1t    = (u16*)(ws + W1T_OFF);
  u16* w2t    = (u16*)(ws + W2T_OFF);
  float* y_ws = (float*)(ws + Y_OFF);
  float* xa_ws= (float*)(ws + XA_OFF);
  float* av_ws= (float*)(ws + AV_OFF);
  float* q_ws = (float*)(ws + Q_OFF);
  float* k_ws = (float*)(ws + K_OFF);
  float* v_ws = (float*)(ws + V_OFF);
  float* cr_ws= (float*)(ws + CR_OFF);

  k_transpose_bf16<<<dim3(24, 24), dim3(32, 8), 0, stream>>>(fc1_w, w1t);
  k_transpose_bf16<<<dim3(24, 24), dim3(32, 8), 0, stream>>>(fc2_w, w2t);
  k_token_a<<<1024, 256, 0, stream>>>(x, am_lin_w, am_lin_b, am_qkv_w, am_qkv_b,
                                      ad_w, ad_b, y_ws, xa_ws, q_ws, k_ws, v_ws);
  k_attn<<<1024, 320, 0, stream>>>(q_ws, k_ws, v_ws, av_ws);
  k_token_c<<<M_TOT, 256, 0, stream>>>(x, y_ws, av_ws, am_proj_w, am_proj_b,
                                       am_end_w, am_end_b, am_ln_g, am_ln_b,
                                       ln2_g, ln2_b, h_ws);
  k_adapter<8><<<128, 256, 0, stream>>>(xa_ws, b2_w, b2_b, b2_bn_g, b2_bn_b, sz_cw,
                                        sz_cr_w, sz_cr_b, sz_ci_w, sz_ci_b,
                                        sz_bn1_g, sz_bn1_b, sz_bn2_g, sz_bn2_b,
                                        c2_w, c2_b, c4_w, c4_b, bn_g, bn_b, cr_ws, 0);
  k_adapter<16><<<128, 256, 0, stream>>>(xa_ws, b1_w, b1_b, b1_bn_g, b1_bn_b, sx_cw,
                                         sx_cr_w, sx_cr_b, sx_ci_w, sx_ci_b,
                                         sx_bn1_g, sx_bn1_b, sx_bn2_g, sx_bn2_b,
                                         c1_w, c1_b, c3_w, c3_b, bn_g, bn_b, cr_ws, 64);
  k_gemm<1><<<1920, 256, 0, stream>>>(h_ws, w1t, fc1_b, g1_ws, nullptr, nullptr, nullptr, nullptr);
  k_gemm<2><<<1920, 256, 0, stream>>>(g1_ws, w2t, fc2_b, nullptr, (float*)d_out, au_w, au_b, cr_ws);
}

// Round 3
// 716.616 us; speedup vs baseline: 1.1204x; 1.1204x over previous
//
// SGBlock fused forward, MI355X (gfx950).
// R1: GEMMs rebuilt — BK=64, double-buffered 2-phase pipeline (T3 minimal),
//     T2 XOR-swizzle (pre-swizzled global src + swizzled ds_read), T1 XCD swizzle.
// R2: identical resubmit (R1 bench was lost to GPU acquisition timeout).
#include <hip/hip_runtime.h>
#include <hip/hip_bf16.h>

typedef unsigned short u16;
typedef __bf16 bf16x8 __attribute__((ext_vector_type(8)));
typedef float f32x4 __attribute__((ext_vector_type(4)));

#define B_    128
#define N_TOK 320
#define D_    768
#define M_TOT (B_ * N_TOK)   // 40960

// ---------------- helpers ----------------
__device__ __forceinline__ u16 f2b(float x) {
  __hip_bfloat16 t = __float2bfloat16(x);
  return *reinterpret_cast<u16*>(&t);
}

typedef const __attribute__((address_space(1))) void* gas1_t;
typedef __attribute__((address_space(3))) void* las3_t;
__device__ __forceinline__ void gll16(const void* g, void* l) {
  __builtin_amdgcn_global_load_lds((gas1_t)g, (las3_t)l, 16, 0, 0);
}

// two-value block reduction over 256 threads (4 waves)
__device__ __forceinline__ void block_reduce2(float& a, float& b, float* red, int t) {
  #pragma unroll
  for (int off = 32; off >= 1; off >>= 1) {
    a += __shfl_xor(a, off);
    b += __shfl_xor(b, off);
  }
  int wv = t >> 6;
  __syncthreads();              // protect red from previous use
  if ((t & 63) == 0) { red[wv] = a; red[4 + wv] = b; }
  __syncthreads();
  a = red[0] + red[1] + red[2] + red[3];
  b = red[4] + red[5] + red[6] + red[7];
}

// ---------------- 1: weight transpose fp32[K][N] -> bf16[N][K] ----------------
__global__ __launch_bounds__(256) void k_transpose_bf16(const float* __restrict__ in,
                                                        u16* __restrict__ out) {
  __shared__ float tile[32][33];
  int c0 = blockIdx.x * 32, r0 = blockIdx.y * 32;
  int tx = threadIdx.x, ty = threadIdx.y;
  #pragma unroll
  for (int k = 0; k < 4; k++)
    tile[ty + k * 8][tx] = in[(size_t)(r0 + ty + k * 8) * 768 + c0 + tx];
  __syncthreads();
  #pragma unroll
  for (int k = 0; k < 4; k++)
    out[(size_t)(c0 + ty + k * 8) * 768 + r0 + tx] = f2b(tile[tx][ty + k * 8]);
}

// ---------------- 2: per-token y = relu(x@lin_w+b), xa = x@ad_w+b, qkv ----------------
__global__ __launch_bounds__(256) void k_token_a(
    const float* __restrict__ x,
    const float* __restrict__ lin_w, const float* __restrict__ lin_b,
    const float* __restrict__ qkv_w, const float* __restrict__ qkv_b,
    const float* __restrict__ ad_w, const float* __restrict__ ad_b,
    float* __restrict__ y_out, float* __restrict__ xa_out,
    float* __restrict__ q_out, float* __restrict__ k_out, float* __restrict__ v_out) {
  __shared__ __align__(16) float w_lds[16 * 768];   // [j][e], j<8: lin_w col, j>=8: ad_w col
  int t = threadIdx.x;
  for (int i = t; i < 6144; i += 256) {
    w_lds[(i & 7) * 768 + (i >> 3)] = lin_w[i];
    w_lds[((i & 7) + 8) * 768 + (i >> 3)] = ad_w[i];
  }
  __syncthreads();
  int wave = t >> 6, lane = t & 63;
  for (int it = 0; it < 10; ++it) {
    int tok = blockIdx.x * 4 + wave + it * 4096;
    const float* xr = x + (size_t)tok * 768;
    float p[16];
    #pragma unroll
    for (int j = 0; j < 16; j++) p[j] = 0.f;
    #pragma unroll
    for (int u = 0; u < 3; u++) {
      float4 xv = *reinterpret_cast<const float4*>(xr + u * 256 + lane * 4);
      #pragma unroll
      for (int j = 0; j < 16; j++) {
        float4 wv = *reinterpret_cast<const float4*>(&w_lds[j * 768 + u * 256 + lane * 4]);
        p[j] += xv.x * wv.x + xv.y * wv.y + xv.z * wv.z + xv.w * wv.w;
      }
    }
    #pragma unroll
    for (int j = 0; j < 16; j++) {
      #pragma unroll
      for (int off = 32; off >= 1; off >>= 1) p[j] += __shfl_xor(p[j], off);
    }
    float yv[8];
    #pragma unroll
    for (int j = 0; j < 8; j++) yv[j] = fmaxf(p[j] + lin_b[j], 0.f);
    if (lane == 0) {
      #pragma unroll
      for (int j = 0; j < 8; j++) {
        y_out[(size_t)tok * 8 + j] = yv[j];
        xa_out[(size_t)tok * 8 + j] = p[8 + j] + ad_b[j];
      }
    }
    if (lane < 24) {
      float o = qkv_b[lane];
      #pragma unroll
      for (int j = 0; j < 8; j++) o += yv[j] * qkv_w[j * 24 + lane];
      int b = tok / 320, n = tok % 320;
      int hh = lane & 7;
      size_t idx = ((size_t)b * 8 + hh) * 320 + n;
      if (lane < 8) q_out[idx] = o;
      else if (lane < 16) k_out[idx] = o;
      else v_out[idx] = o;
    }
  }
}

// ---------------- 3: attention (dh=1): av[b,n,h] = softmax_m(q_n k_m) . v ----------------
__global__ __launch_bounds__(320) void k_attn(
    const float* __restrict__ q, const float* __restrict__ k,
    const float* __restrict__ v, float* __restrict__ av) {
  __shared__ float ks[320], vs[320];
  __shared__ float red[12];
  int bh = blockIdx.x;          // b*8+h
  int n = threadIdx.x;          // 0..319
  float kk = k[(size_t)bh * 320 + n];
  ks[n] = kk;
  vs[n] = v[(size_t)bh * 320 + n];
  float qn = q[(size_t)bh * 320 + n];
  float mx = kk, mn = kk;
  #pragma unroll
  for (int off = 32; off >= 1; off >>= 1) {
    mx = fmaxf(mx, __shfl_xor(mx, off));
    mn = fminf(mn, __shfl_xor(mn, off));
  }
  int wave = n >> 6;
  if ((n & 63) == 0) { red[wave] = mx; red[5 + wave] = mn; }
  __syncthreads();
  if (n == 0) {
    float a = red[0], b = red[5];
    #pragma unroll
    for (int w = 1; w < 5; w++) { a = fmaxf(a, red[w]); b = fminf(b, red[5 + w]); }
    red[10] = a; red[11] = b;
  }
  __syncthreads();
  float kmax = red[10], kmin = red[11];
  float m1 = fmaxf(qn * kmax, qn * kmin);
  float se = 0.f, sv = 0.f;
  for (int m = 0; m < 320; m++) {
    float e = __expf(qn * ks[m] - m1);
    se += e;
    sv += e * vs[m];
  }
  int b_ = bh >> 3, h_ = bh & 7;
  av[(((size_t)b_ * 320) + n) * 8 + h_] = sv / se;
}

// ---------------- 4: residual + LN + LN2 -> h (bf16) ----------------
__global__ __launch_bounds__(256) void k_token_c(
    const float* __restrict__ x, const float* __restrict__ y_ws, const float* __restrict__ av_ws,
    const float* __restrict__ proj_w, const float* __restrict__ proj_b,
    const float* __restrict__ end_w, const float* __restrict__ end_b,
    const float* __restrict__ g1ln, const float* __restrict__ b1ln,
    const float* __restrict__ g2ln, const float* __restrict__ b2ln,
    u16* __restrict__ hout) {
  __shared__ float red[8];
  size_t tok = blockIdx.x;
  int t = threadIdx.x;
  float u[8];
  #pragma unroll
  for (int o = 0; o < 8; o++) {
    float a = proj_b[o];
    #pragma unroll
    for (int j = 0; j < 8; j++) a += av_ws[tok * 8 + j] * proj_w[j * 8 + o];
    u[o] = a + y_ws[tok * 8 + o];
  }
  float tv[3];
  #pragma unroll
  for (int c = 0; c < 3; c++) {
    int d = t + c * 256;
    float a = x[tok * 768 + d] + end_b[d];
    #pragma unroll
    for (int j = 0; j < 8; j++) a += u[j] * end_w[j * 768 + d];
    tv[c] = a;
  }
  float s = tv[0] + tv[1] + tv[2];
  float s2 = tv[0] * tv[0] + tv[1] * tv[1] + tv[2] * tv[2];
  block_reduce2(s, s2, red, t);
  float m1 = s * (1.f / 768.f);
  float inv1 = rsqrtf(fmaxf(s2 * (1.f / 768.f) - m1 * m1, 0.f) + 1e-5f);
  float x0[3];
  #pragma unroll
  for (int c = 0; c < 3; c++) {
    int d = t + c * 256;
    x0[c] = (tv[c] - m1) * inv1 * g1ln[d] + b1ln[d];
  }
  s = x0[0] + x0[1] + x0[2];
  s2 = x0[0] * x0[0] + x0[1] * x0[1] + x0[2] * x0[2];
  block_reduce2(s, s2, red, t);
  float m2 = s * (1.f / 768.f);
  float inv2 = rsqrtf(fmaxf(s2 * (1.f / 768.f) - m2 * m2, 0.f) + 1e-5f);
  #pragma unroll
  for (int c = 0; c < 3; c++) {
    int d = t + c * 256;
    float hv = (x0[c] - m2) * inv2 * g2ln[d] + b2ln[d];
    hout[tok * 768 + d] = f2b(hv);
  }
}

// ---------------- 5/6: adapter branch (conv1x1+bn+relu, SGN via direct DFT, convs, bns) ----------------
template <int S>
__global__ __launch_bounds__(256) void k_adapter(
    const float* __restrict__ xa,
    const float* __restrict__ bw, const float* __restrict__ bb,
    const float* __restrict__ bng0, const float* __restrict__ bnb0,
    const float* __restrict__ cw,
    const float* __restrict__ crw, const float* __restrict__ crb,
    const float* __restrict__ ciw, const float* __restrict__ cib,
    const float* __restrict__ bn1g, const float* __restrict__ bn1b,
    const float* __restrict__ bn2g, const float* __restrict__ bn2b,
    const float* __restrict__ cvw, const float* __restrict__ cvb,
    const float* __restrict__ c3w, const float* __restrict__ c3b,
    const float* __restrict__ bng, const float* __restrict__ bnb,
    float* __restrict__ crout, int tok_off) {
  constexpr int NF = S / 2 + 1;
  constexpr int P = S * S;
  constexpr int NFREQ = S * NF * 8;
  __shared__ float xr[8 * P];
  __shared__ float x1[8 * P];
  __shared__ float xo[8 * P];
  __shared__ float bufA[NFREQ * 2];
  __shared__ float bufB[NFREQ * 2];
  __shared__ float cosT[S], sinT[S];
  const int b = blockIdx.x, t = threadIdx.x;
  const float binv = rsqrtf(1.f + 1e-5f);
  if (t < S) {
    float ang = 6.28318530717958647692f * (float)t / (float)S;
    cosT[t] = cosf(ang);
    sinT[t] = sinf(ang);
  }
  for (int i = t; i < 8 * P; i += 256) {
    int c = i / P, p = i % P;
    xr[i] = xa[((size_t)b * N_TOK + tok_off + p) * 8 + c];
  }
  __syncthreads();
  // b-conv 1x1 + bn + relu -> x1
  for (int i = t; i < 8 * P; i += 256) {
    int c = i / P, p = i % P;
    float a = bb[c];
    #pragma unroll
    for (int j = 0; j < 8; j++) a += xr[j * P + p] * bw[c * 8 + j];
    a = a * (bng0[c] * binv) + bnb0[c];
    x1[i] = fmaxf(a, 0.f);
  }
  __syncthreads();
  // forward rfft over h (axis2): Ra[w][v][c]
  for (int i = t; i < NFREQ; i += 256) {
    int c = i & 7, v = (i >> 3) % NF, w = i / (8 * NF);
    float re = 0.f, im = 0.f;
    #pragma unroll
    for (int h = 0; h < S; h++) {
      float xv = x1[c * P + h * S + w];
      int idx = (v * h) % S;
      re += xv * cosT[idx];
      im -= xv * sinT[idx];
    }
    bufA[i * 2] = re;
    bufA[i * 2 + 1] = im;
  }
  __syncthreads();
  // forward fft over w (axis1) -> F[u][v][c], ortho scale 1/S
  for (int i = t; i < NFREQ; i += 256) {
    int c = i & 7, v = (i >> 3) % NF, u = i / (8 * NF);
    float re = 0.f, im = 0.f;
    #pragma unroll
    for (int w = 0; w < S; w++) {
      float ar = bufA[((w * NF + v) * 8 + c) * 2];
      float ai = bufA[((w * NF + v) * 8 + c) * 2 + 1];
      int idx = (u * w) % S;
      float cs = cosT[idx], sn = sinT[idx];
      re += ar * cs + ai * sn;
      im += ai * cs - ar * sn;
    }
    bufB[i * 2] = re * (1.f / S);
    bufB[i * 2 + 1] = im * (1.f / S);
  }
  __syncthreads();
  // channel mix (conv1x1 + bn + relu on re/im), then complex weight cw
  for (int i = t; i < NFREQ; i += 256) {
    int c = i & 7;
    int uv = i >> 3;
    float fr = crb[c], fi = cib[c];
    #pragma unroll
    for (int j = 0; j < 8; j++) {
      fr += bufB[(uv * 8 + j) * 2] * crw[c * 8 + j];
      fi += bufB[(uv * 8 + j) * 2 + 1] * ciw[c * 8 + j];
    }
    fr = fmaxf(fr * (bn1g[c] * binv) + bn1b[c], 0.f);
    fi = fmaxf(fi * (bn2g[c] * binv) + bn2b[c], 0.f);
    float cwr = cw[i * 2], cwi = cw[i * 2 + 1];
    bufA[i * 2] = fr * cwr - fi * cwi;
    bufA[i * 2 + 1] = fr * cwi + fi * cwr;
  }
  __syncthreads();
  // inverse fft over u -> T[w][v][c]
  for (int i = t; i < NFREQ; i += 256) {
    int c = i & 7, v = (i >> 3) % NF, w = i / (8 * NF);
    float re = 0.f, im = 0.f;
    #pragma unroll
    for (int u = 0; u < S; u++) {
      float gr = bufA[((u * NF + v) * 8 + c) * 2];
      float gi = bufA[((u * NF + v) * 8 + c) * 2 + 1];
      int idx = (u * w) % S;
      float cs = cosT[idx], sn = sinT[idx];
      re += gr * cs - gi * sn;
      im += gi * cs + gr * sn;
    }
    bufB[((w * NF + v) * 8 + c) * 2] = re;
    bufB[((w * NF + v) * 8 + c) * 2 + 1] = im;
  }
  __syncthreads();
  // inverse real transform over v (c2r: DC/Nyquist imag discarded), scale 1/S, + x1
  for (int i = t; i < 8 * P; i += 256) {
    int c = i / P, p = i % P, h = p / S, w = p % S;
    float acc = bufB[((w * NF + 0) * 8 + c) * 2];
    float ny = bufB[((w * NF + (NF - 1)) * 8 + c) * 2];
    acc += (h & 1) ? -ny : ny;
    #pragma unroll
    for (int v = 1; v < NF - 1; v++) {
      int idx = (v * h) % S;
      acc += 2.f * (bufB[((w * NF + v) * 8 + c) * 2] * cosT[idx] -
                    bufB[((w * NF + v) * 8 + c) * 2 + 1] * sinT[idx]);
    }
    xo[i] = acc * (1.f / S) + x1[i];
  }
  __syncthreads();
  // conv1x1+bn+relu, + conv3x3(xr), bn+relu, store tokens
  for (int i = t; i < 8 * P; i += 256) {
    int c = i / P, p = i % P, h = p / S, w = p % S;
    float a = cvb[c];
    #pragma unroll
    for (int j = 0; j < 8; j++) a += xo[j * P + p] * cvw[c * 8 + j];
    a = fmaxf(a * (bng[c] * binv) + bnb[c], 0.f);
    float x2 = c3b[c];
    #pragma unroll
    for (int j = 0; j < 8; j++) {
      #pragma unroll
      for (int dy = 0; dy < 3; dy++) {
        int hh = h + dy - 1;
        if (hh < 0 || hh >= S) continue;
        #pragma unroll
        for (int dx = 0; dx < 3; dx++) {
          int ww = w + dx - 1;
          if (ww < 0 || ww >= S) continue;
          x2 += xr[j * P + hh * S + ww] * c3w[((c * 8 + j) * 3 + dy) * 3 + dx];
        }
      }
    }
    float fin = (a + x2) * (bng[c] * binv) + bnb[c];
    crout[((size_t)b * N_TOK + tok_off + p) * 8 + c] = fmaxf(fin, 0.f);
  }
}

// ---------------- 7/8: bf16 MFMA GEMM, 128x128 tile, BK=64, dbuf 2-phase ----------------
// A: [40960][768] bf16 row-major; Bt: [768][768] bf16 (col of output = row of Bt).
// LDS tiles [128 rows][64 elems] bf16 (128 B rows), XOR-swizzle byte^=((row&7)<<4),
// staged via global_load_lds with pre-swizzled global source (rule #21).
// MODE 1: obf = bf16(gelu_exact(acc + bias))          (GEMM1)
// MODE 2: ofp = acc + bias + au_b + cr@au_w           (GEMM2 + adapter epilogue)
template <int MODE>
__global__ __launch_bounds__(256, 2) void k_gemm(
    const u16* __restrict__ A, const u16* __restrict__ Bt,
    const float* __restrict__ bias,
    u16* __restrict__ obf, float* __restrict__ ofp,
    const float* __restrict__ au_w, const float* __restrict__ au_b,
    const float* __restrict__ cr) {
  __shared__ __align__(16) u16 As[2][128 * 64];
  __shared__ __align__(16) u16 Bs[2][128 * 64];
  // T1: bijective XCD-chunked swizzle (nwg=1920, 1920%8==0, chunk=240)
  int orig = blockIdx.x;
  int wgid = (orig & 7) * 240 + (orig >> 3);
  int bm = wgid / 6, bn = wgid % 6;
  int m0 = bm * 128, n0 = bn * 128;
  int t = threadIdx.x, wave = t >> 6, lane = t & 63;
  int wr = wave >> 1, wc = wave & 1;
  const int l15 = lane & 15, l4 = lane >> 4;
  const int swz = (l15 & 7) << 4;        // read-side XOR (row&7 == l15&7 for our frags)

  // Per-thread stage sources: 4 chunks of 16B each for A and B.
  // chunk b = i*256+t; linear LDS byte p=16b; logical q = p ^ (((p>>7)&7)<<4).
  const char* srcA[4];
  const char* srcB[4];
  #pragma unroll
  for (int i = 0; i < 4; i++) {
    int b = i * 256 + t;
    int row = b >> 3;                       // 8 chunks per 128B row
    int colb = ((b & 7) << 4) ^ ((row & 7) << 4);
    srcA[i] = (const char*)A + (size_t)(m0 + row) * 1536 + colb;
    srcB[i] = (const char*)Bt + (size_t)(n0 + row) * 1536 + colb;
  }

  f32x4 acc[4][4];
  #pragma unroll
  for (int mi = 0; mi < 4; mi++)
    #pragma unroll
    for (int ni = 0; ni < 4; ni++) {
      f32x4 z = {0.f, 0.f, 0.f, 0.f};
      acc[mi][ni] = z;
    }

  auto STAGE = [&](int buf, int k0) {
    #pragma unroll
    for (int i = 0; i < 4; i++) {
      int basechunk = i * 256 + wave * 64;
      gll16(srcA[i] + 2 * k0, (void*)&As[buf][basechunk * 8]);
      gll16(srcB[i] + 2 * k0, (void*)&Bs[buf][basechunk * 8]);
    }
  };

  auto COMPUTE = [&](int buf) {
    const char* abase = (const char*)&As[buf][0];
    const char* bbase = (const char*)&Bs[buf][0];
    bf16x8 af[2][4], bf[2][4];
    #pragma unroll
    for (int kk = 0; kk < 2; kk++) {
      int c = kk * 64 + l4 * 16;
      int cs = c ^ swz;
      #pragma unroll
      for (int mi = 0; mi < 4; mi++) {
        int R = wr * 64 + mi * 16 + l15;
        af[kk][mi] = *reinterpret_cast<const bf16x8*>(abase + R * 128 + cs);
      }
      #pragma unroll
      for (int ni = 0; ni < 4; ni++) {
        int R = wc * 64 + ni * 16 + l15;
        bf[kk][ni] = *reinterpret_cast<const bf16x8*>(bbase + R * 128 + cs);
      }
    }
    #pragma unroll
    for (int kk = 0; kk < 2; kk++)
      #pragma unroll
      for (int mi = 0; mi < 4; mi++)
        #pragma unroll
        for (int ni = 0; ni < 4; ni++)
          acc[mi][ni] = __builtin_amdgcn_mfma_f32_16x16x32_bf16(af[kk][mi], bf[kk][ni],
                                                                acc[mi][ni], 0, 0, 0);
  };

  STAGE(0, 0);
  __syncthreads();                       // compiler emits vmcnt(0) drain before barrier
  int cur = 0;
  #pragma unroll 1
  for (int s = 0; s < 11; ++s) {
    STAGE(cur ^ 1, (s + 1) * 64);        // issue next-tile loads BEFORE compute
    COMPUTE(cur);                        // MFMA hides the in-flight loads
    __syncthreads();                     // drain vmcnt, flip buffers
    cur ^= 1;
  }
  COMPUTE(cur);

  // epilogue: C/D layout col = lane&15, row = 4*(lane>>4)+reg
  #pragma unroll
  for (int mi = 0; mi < 4; mi++) {
    #pragma unroll
    for (int ni = 0; ni < 4; ni++) {
      int colg = n0 + wc * 64 + ni * 16 + l15;
      #pragma unroll
      for (int rg = 0; rg < 4; rg++) {
        int rowg = m0 + wr * 64 + mi * 16 + l4 * 4 + rg;
        float vv = acc[mi][ni][rg] + bias[colg];
        if constexpr (MODE == 1) {
          vv = 0.5f * vv * (1.f + erff(vv * 0.70710678118654752f));
          obf[(size_t)rowg * 768 + colg] = f2b(vv);
        } else {
          vv += au_b[colg];
          const float* crr = cr + (size_t)rowg * 8;
          #pragma unroll
          for (int j = 0; j < 8; j++) vv += crr[j] * au_w[j * 768 + colg];
          ofp[(size_t)rowg * 768 + colg] = vv;
        }
      }
    }
  }
}

// ---------------- launch ----------------
extern "C" void kernel_launch(void* const* d_in, const int* in_sizes, int n_in,
                              void* d_out, int out_size, void* d_ws, size_t ws_size,
                              hipStream_t stream) {
  const float* x        = (const float*)d_in[0];
  const float* am_lin_w = (const float*)d_in[1];
  const float* am_lin_b = (const float*)d_in[2];
  const float* am_qkv_w = (const float*)d_in[3];
  const float* am_qkv_b = (const float*)d_in[4];
  const float* am_proj_w= (const float*)d_in[5];
  const float* am_proj_b= (const float*)d_in[6];
  const float* am_end_w = (const float*)d_in[7];
  const float* am_end_b = (const float*)d_in[8];
  const float* am_ln_g  = (const float*)d_in[9];
  const float* am_ln_b  = (const float*)d_in[10];
  const float* ln2_g    = (const float*)d_in[11];
  const float* ln2_b    = (const float*)d_in[12];
  const float* fc1_w    = (const float*)d_in[13];
  const float* fc1_b    = (const float*)d_in[14];
  const float* fc2_w    = (const float*)d_in[15];
  const float* fc2_b    = (const float*)d_in[16];
  const float* ad_w     = (const float*)d_in[17];
  const float* ad_b     = (const float*)d_in[18];
  const float* au_w     = (const float*)d_in[19];
  const float* au_b     = (const float*)d_in[20];
  const float* b1_w     = (const float*)d_in[21];
  const float* b1_b     = (const float*)d_in[22];
  const float* b1_bn_g  = (const float*)d_in[23];
  const float* b1_bn_b  = (const float*)d_in[24];
  const float* b2_w     = (const float*)d_in[25];
  const float* b2_b     = (const float*)d_in[26];
  const float* b2_bn_g  = (const float*)d_in[27];
  const float* b2_bn_b  = (const float*)d_in[28];
  const float* sx_cw    = (const float*)d_in[29];
  const float* sx_cr_w  = (const float*)d_in[30];
  const float* sx_cr_b  = (const float*)d_in[31];
  const float* sx_ci_w  = (const float*)d_in[32];
  const float* sx_ci_b  = (const float*)d_in[33];
  const float* sx_bn1_g = (const float*)d_in[34];
  const float* sx_bn1_b = (const float*)d_in[35];
  const float* sx_bn2_g = (const float*)d_in[36];
  const float* sx_bn2_b = (const float*)d_in[37];
  const float* sz_cw    = (const float*)d_in[38];
  const float* sz_cr_w  = (const float*)d_in[39];
  const float* sz_cr_b  = (const float*)d_in[40];
  const float* sz_ci_w  = (const float*)d_in[41];
  const float* sz_ci_b  = (const float*)d_in[42];
  const float* sz_bn1_g = (const float*)d_in[43];
  const float* sz_bn1_b = (const float*)d_in[44];
  const float* sz_bn2_g = (const float*)d_in[45];
  const float* sz_bn2_b = (const float*)d_in[46];
  const float* c1_w     = (const float*)d_in[47];
  const float* c1_b     = (const float*)d_in[48];
  const float* c2_w     = (const float*)d_in[49];
  const float* c2_b     = (const float*)d_in[50];
  const float* c3_w     = (const float*)d_in[51];
  const float* c3_b     = (const float*)d_in[52];
  const float* c4_w     = (const float*)d_in[53];
  const float* c4_b     = (const float*)d_in[54];
  const float* bn_g     = (const float*)d_in[55];
  const float* bn_b     = (const float*)d_in[56];

  char* ws = (char*)d_ws;
  constexpr size_t H_OFF   = 0;                         // h bf16 [40960][768]
  constexpr size_t G1_OFF  = 62914560;                  // g1 bf16 [40960][768]
  constexpr size_t W1T_OFF = 125829120;                 // fc1_w^T bf16 [768][768]
  constexpr size_t W2T_OFF = W1T_OFF + 1179648;
  constexpr size_t Y_OFF   = W2T_OFF + 1179648;         // y [40960][8] f32
  constexpr size_t XA_OFF  = Y_OFF + 1310720;
  constexpr size_t AV_OFF  = XA_OFF + 1310720;
  constexpr size_t Q_OFF   = AV_OFF + 1310720;
  constexpr size_t K_OFF   = Q_OFF + 1310720;
  constexpr size_t V_OFF   = K_OFF + 1310720;
  constexpr size_t CR_OFF  = V_OFF + 1310720;

  u16* h_ws   = (u16*)(ws + H_OFF);
  u16* g1_ws  = (u16*)(ws + G1_OFF);
  u16* w1t    = (u16*)(ws + W1T_OFF);
  u16* w2t    = (u16*)(ws + W2T_OFF);
  float* y_ws = (float*)(ws + Y_OFF);
  float* xa_ws= (float*)(ws + XA_OFF);
  float* av_ws= (float*)(ws + AV_OFF);
  float* q_ws = (float*)(ws + Q_OFF);
  float* k_ws = (float*)(ws + K_OFF);
  float* v_ws = (float*)(ws + V_OFF);
  float* cr_ws= (float*)(ws + CR_OFF);

  k_transpose_bf16<<<dim3(24, 24), dim3(32, 8), 0, stream>>>(fc1_w, w1t);
  k_transpose_bf16<<<dim3(24, 24), dim3(32, 8), 0, stream>>>(fc2_w, w2t);
  k_token_a<<<1024, 256, 0, stream>>>(x, am_lin_w, am_lin_b, am_qkv_w, am_qkv_b,
                                      ad_w, ad_b, y_ws, xa_ws, q_ws, k_ws, v_ws);
  k_attn<<<1024, 320, 0, stream>>>(q_ws, k_ws, v_ws, av_ws);
  k_token_c<<<M_TOT, 256, 0, stream>>>(x, y_ws, av_ws, am_proj_w, am_proj_b,
                                       am_end_w, am_end_b, am_ln_g, am_ln_b,
                                       ln2_g, ln2_b, h_ws);
  k_adapter<8><<<128, 256, 0, stream>>>(xa_ws, b2_w, b2_b, b2_bn_g, b2_bn_b, sz_cw,
                                        sz_cr_w, sz_cr_b, sz_ci_w, sz_ci_b,
                                        sz_bn1_g, sz_bn1_b, sz_bn2_g, sz_bn2_b,
                                        c2_w, c2_b, c4_w, c4_b, bn_g, bn_b, cr_ws, 0);
  k_adapter<16><<<128, 256, 0, stream>>>(xa_ws, b1_w, b1_b, b1_bn_g, b1_bn_b, sx_cw,
                                         sx_cr_w, sx_cr_b, sx_ci_w, sx_ci_b,
                                         sx_bn1_g, sx_bn1_b, sx_bn2_g, sx_bn2_b,
                                         c1_w, c1_b, c3_w, c3_b, bn_g, bn_b, cr_ws, 64);
  k_gemm<1><<<1920, 256, 0, stream>>>(h_ws, w1t, fc1_b, g1_ws, nullptr, nullptr, nullptr, nullptr);
  k_gemm<2><<<1920, 256, 0, stream>>>(g1_ws, w2t, fc2_b, nullptr, (float*)d_out, au_w, au_b, cr_ws);
}